// Round 2
// baseline (777.870 us; speedup 1.0000x reference)
//
#include <hip/hip_runtime.h>
#include <hip/hip_bf16.h>

// Problem constants (match reference setup_inputs)
#define H_DIM   4096   // input features (K of the GEMM)
#define M_DIM   4096   // output features (W rows = C cols)
#define N_ROWS  8192   // B*S flattened x rows
#define NNZ_ROW 2048

typedef __bf16 bf16x8 __attribute__((ext_vector_type(8)));
typedef float  f32x4  __attribute__((ext_vector_type(4)));
typedef unsigned int u32;
typedef u32 u32x4 __attribute__((ext_vector_type(4)));

// fp32 -> bf16 round-to-nearest-even on raw bits (decode path)
__device__ __forceinline__ unsigned short f2bf(float f) {
    unsigned int u = __float_as_uint(f);
    u += 0x7fffu + ((u >> 16) & 1u);
    return (unsigned short)(u >> 16);
}

// async global->LDS, 16B/lane; LDS dst must be wave-uniform base + lane*16
__device__ __forceinline__ void gld_lds16(const void* g, void* l) {
    __builtin_amdgcn_global_load_lds(
        (__attribute__((address_space(1))) const void*)g,
        (__attribute__((address_space(3))) void*)l,
        16, 0, 0);
}

// ---------------------------------------------------------------------------
// Kernel 1: decode CSR row -> dense bf16 row via LDS scatter, coalesced store.
// ---------------------------------------------------------------------------
__global__ __launch_bounds__(256) void decode_w_kernel(
        const float* __restrict__ values,
        const int*   __restrict__ col_idx,
        unsigned short* __restrict__ W) {
    __shared__ unsigned short rowbuf[H_DIM];     // 8 KiB
    const int m = blockIdx.x;
    const int t = threadIdx.x;

    uint4 z = make_uint4(0u, 0u, 0u, 0u);
    ((uint4*)rowbuf)[t]       = z;
    ((uint4*)rowbuf)[t + 256] = z;
    __syncthreads();

    const long base = (long)m * NNZ_ROW;
    #pragma unroll
    for (int j = 0; j < NNZ_ROW; j += 256) {
        float v = values[base + j + t];
        int   c = col_idx[base + j + t];
        rowbuf[c] = f2bf(v);
    }
    __syncthreads();

    uint4* out = (uint4*)(W + (long)m * H_DIM);
    out[t]       = ((uint4*)rowbuf)[t];
    out[t + 256] = ((uint4*)rowbuf)[t + 256];
}

// ---------------------------------------------------------------------------
// Kernel 2: C[N_ROWS, M_DIM] = X_fp32[N_ROWS, K] @ W_bf16[M_DIM, K]^T.
// A staged fp32 direct from x (convert fused, v_perm truncate); B bf16.
// A LDS rows are chunk-rotated by (row&7) so f32 b128 frag reads are
// bank-balanced; staging picks the rotated global chunk per lane so the
// global_load_lds wave-uniform layout still holds.
// 1D grid with 8x8 tile-group swizzle for L2 locality.
// ---------------------------------------------------------------------------
__global__ __launch_bounds__(256) void gemm_fused_kernel(
        const float* __restrict__ A,            // x fp32 [N_ROWS][H_DIM]
        const unsigned short* __restrict__ B,   // W bf16 [M_DIM][H_DIM]
        float* __restrict__ C) {                // [N_ROWS][M_DIM] fp32
    __shared__ float          As[128 * 32];     // 16 KiB (rotated chunks)
    __shared__ unsigned short Bs[128 * 32];     // 8 KiB

    const int t    = threadIdx.x;
    const int lane = t & 63;
    const int wid  = t >> 6;
    const int wm   = wid >> 1;   // wave row 0..1
    const int wn   = wid & 1;    // wave col 0..1

    // ---- block swizzle: bands of 8 row-tiles, 8x8 groups, row-major in group
    const int gid  = blockIdx.x;          // 0..2047
    const int band = gid >> 8;            // 0..7   (8 row-tiles per band)
    const int rem  = gid & 255;
    const int cg   = rem >> 6;            // 0..3   (8 col-tiles per group)
    const int lid  = rem & 63;
    const long row0 = ((long)band * 8 + (lid >> 3)) * 128;
    const long col0 = ((long)cg   * 8 + (lid & 7))  * 128;

    // ---- A staging (fp32, 4 shots x 32 rows, 16B/lane, rotated chunk pick)
    const int ar = t >> 3;                // local row 0..31
    const int ap = t & 7;                 // LDS chunk position 0..7
    const int ac = (ap - ar) & 7;         // global 16B-chunk held at ap
    const float* Ag = A + (row0 + ar) * H_DIM + ac * 4;
    float* Al = &As[t * 4];               // byte offset t*16

    // ---- B staging (bf16, 2 shots x 64 rows, 16B/lane, linear)
    const int br = t >> 2;                // local row 0..63
    const int bc = (t & 3) * 8;           // col {0,8,16,24}
    const unsigned short* Bg = B + (col0 + br) * H_DIM + bc;
    unsigned short* Bl = &Bs[t * 8];

    f32x4 acc[4][4];
    #pragma unroll
    for (int i = 0; i < 4; ++i)
        #pragma unroll
        for (int j = 0; j < 4; ++j)
            acc[i][j] = (f32x4)0.0f;

    const int fr = lane & 15;             // row within 16-row band
    const int jq = lane >> 4;             // k-quad 0..3 (k = jq*8 .. jq*8+7)
    const unsigned short* Brd = &Bs[(wn * 64 + fr) * 32 + jq * 8];

    for (int k0 = 0; k0 < H_DIM; k0 += 32) {
        __syncthreads();                  // prev tile consumed
        #pragma unroll
        for (int s = 0; s < 4; ++s)
            gld_lds16(Ag + k0 + s * 32 * H_DIM, Al + s * 1024);
        #pragma unroll
        for (int s = 0; s < 2; ++s)
            gld_lds16(Bg + k0 + s * 64 * H_DIM, Bl + s * 2048);
        __syncthreads();                  // staging drained

        bf16x8 a[4], b[4];
        #pragma unroll
        for (int i = 0; i < 4; ++i) {
            const int r = wm * 64 + i * 16 + fr;
            const f32x4* rowp = (const f32x4*)&As[r * 32];
            union { f32x4 f; u32x4 u; } lo, hi;
            lo.f = rowp[(2 * jq     + r) & 7];
            hi.f = rowp[(2 * jq + 1 + r) & 7];
            union { u32 w[4]; bf16x8 v; } cv;
            cv.w[0] = __builtin_amdgcn_perm(lo.u.y, lo.u.x, 0x07060302u);
            cv.w[1] = __builtin_amdgcn_perm(lo.u.w, lo.u.z, 0x07060302u);
            cv.w[2] = __builtin_amdgcn_perm(hi.u.y, hi.u.x, 0x07060302u);
            cv.w[3] = __builtin_amdgcn_perm(hi.u.w, hi.u.z, 0x07060302u);
            a[i] = cv.v;
        }
        #pragma unroll
        for (int j = 0; j < 4; ++j)
            b[j] = *(const bf16x8*)(Brd + j * 16 * 32);

        #pragma unroll
        for (int i = 0; i < 4; ++i)
            #pragma unroll
            for (int j = 0; j < 4; ++j)
                acc[i][j] = __builtin_amdgcn_mfma_f32_16x16x32_bf16(
                                a[i], b[j], acc[i][j], 0, 0, 0);
    }

    // epilogue: D col = lane&15, row = (lane>>4)*4 + reg  [m89/m91 verified]
    const int dcol = lane & 15;
    const int drow = (lane >> 4) * 4;
    #pragma unroll
    for (int i = 0; i < 4; ++i) {
        const long r = row0 + wm * 64 + i * 16 + drow;
        #pragma unroll
        for (int j = 0; j < 4; ++j) {
            float* cp = C + r * M_DIM + (col0 + wn * 64 + j * 16 + dcol);
            #pragma unroll
            for (int q = 0; q < 4; ++q)
                __builtin_nontemporal_store(acc[i][j][q], cp + q * (long)M_DIM);
        }
    }
}

// ---------------------------------------------------------------------------
// Fallback if ws can't hold W: naive fp32 sparse dot (correct, slow).
// ---------------------------------------------------------------------------
__global__ __launch_bounds__(256) void naive_kernel(
        const float* __restrict__ x, const float* __restrict__ vals,
        const int* __restrict__ cols, float* __restrict__ out) {
    const long idx = blockIdx.x * 256L + threadIdx.x;
    const int  m   = (int)(idx & (M_DIM - 1));
    const long n   = idx >> 12;
    const float* xr = x + n * H_DIM;
    const float* v  = vals + (long)m * NNZ_ROW;
    const int*   c  = cols + (long)m * NNZ_ROW;
    float s = 0.f;
    for (int j = 0; j < NNZ_ROW; ++j) s += v[j] * xr[c[j]];
    out[idx] = s;
}

extern "C" void kernel_launch(void* const* d_in, const int* in_sizes, int n_in,
                              void* d_out, int out_size, void* d_ws, size_t ws_size,
                              hipStream_t stream) {
    const float* x       = (const float*)d_in[0];
    const float* values  = (const float*)d_in[1];
    const int*   col_idx = (const int*)d_in[2];
    float* out = (float*)d_out;

    const size_t wbytes = (size_t)M_DIM * H_DIM * sizeof(unsigned short); // 33.5 MB

    if (ws_size >= wbytes) {
        unsigned short* W = (unsigned short*)d_ws;
        decode_w_kernel<<<M_DIM, 256, 0, stream>>>(values, col_idx, W);
        gemm_fused_kernel<<<(N_ROWS / 128) * (M_DIM / 128), 256, 0, stream>>>(
            x, W, out);
    } else {
        naive_kernel<<<(int)((long)N_ROWS * M_DIM / 256), 256, 0, stream>>>(
            x, values, col_idx, out);
    }
}

// Round 4
// 614.447 us; speedup vs baseline: 1.2660x; 1.2660x over previous
//
#include <hip/hip_runtime.h>
#include <hip/hip_bf16.h>

// Problem constants (match reference setup_inputs)
#define H_DIM   4096   // input features (K of the GEMM)
#define M_DIM   4096   // output features (W rows = C cols)
#define N_ROWS  8192   // B*S flattened x rows
#define NNZ_ROW 2048

typedef __bf16 bf16x8 __attribute__((ext_vector_type(8)));
typedef float  f32x4  __attribute__((ext_vector_type(4)));

// fp32 -> bf16 round-to-nearest-even on raw bits
__device__ __forceinline__ unsigned short f2bf(float f) {
    unsigned int u = __float_as_uint(f);
    u += 0x7fffu + ((u >> 16) & 1u);
    return (unsigned short)(u >> 16);
}

// async global->LDS, 16B/lane; LDS dst = wave-uniform base + lane*16
__device__ __forceinline__ void gld_lds16(const void* g, void* l) {
    __builtin_amdgcn_global_load_lds(
        (__attribute__((address_space(1))) const void*)g,
        (__attribute__((address_space(3))) void*)l,
        16, 0, 0);
}

// ---------------------------------------------------------------------------
// Kernel 1: decode CSR directly into MFMA B-fragment-major bf16 W.
// Layout: Wf[ct][kc][lane][8] with ct=m>>4, kc=k>>5, lane=jq*16+fr,
//         fr=m&15, jq=(k>>3)&3, j=k&7. A wave's b-frag load is then
//         64 lanes x 16B fully linear (1KB per global_load_dwordx4).
// Block handles 4 consecutive rows (same ct group of 16).
// ---------------------------------------------------------------------------
__global__ __launch_bounds__(256) void decode_w_frag_kernel(
        const float* __restrict__ values,
        const int*   __restrict__ col_idx,
        unsigned short* __restrict__ Wf) {
    __shared__ unsigned short buf[4 * H_DIM];      // 32 KiB
    const int r4 = blockIdx.x;                     // rows 4*r4 .. 4*r4+3
    const int t  = threadIdx.x;

    uint4 z = make_uint4(0u, 0u, 0u, 0u);
    #pragma unroll
    for (int i = 0; i < 8; ++i) ((uint4*)buf)[i * 256 + t] = z;
    __syncthreads();

    #pragma unroll
    for (int rl = 0; rl < 4; ++rl) {
        const long base = ((long)(4 * r4 + rl)) * NNZ_ROW;
        #pragma unroll
        for (int j = 0; j < NNZ_ROW; j += 256) {
            float v = values[base + j + t];
            int   c = col_idx[base + j + t];
            buf[rl * H_DIM + c] = f2bf(v);
        }
    }
    __syncthreads();

    const int ct  = r4 >> 2;
    const int fr0 = (r4 & 3) * 4;
    #pragma unroll
    for (int it = 0; it < 8; ++it) {
        const int task = it * 256 + t;             // 0..2047
        const int rl = task & 3;
        const int jq = (task >> 2) & 3;
        const int kc = task >> 4;                  // 0..127
        uint4 v = *(const uint4*)&buf[rl * H_DIM + kc * 32 + jq * 8];
        const long dst = (((long)ct * 128 + kc) * 64 + jq * 16 + fr0 + rl) * 8;
        *(uint4*)&Wf[dst] = v;
    }
}

// ---------------------------------------------------------------------------
// Kernel 2: x fp32 -> bf16 row-major, 8 elems/thread, 16B stores.
// ---------------------------------------------------------------------------
__global__ __launch_bounds__(256) void convert_x_kernel(
        const float4* __restrict__ x, uint4* __restrict__ xb) {
    const long i = blockIdx.x * 256L + threadIdx.x;
    float4 a = x[2 * i];
    float4 b = x[2 * i + 1];
    union { unsigned short s[8]; uint4 v; } r;
    r.s[0] = f2bf(a.x); r.s[1] = f2bf(a.y); r.s[2] = f2bf(a.z); r.s[3] = f2bf(a.w);
    r.s[4] = f2bf(b.x); r.s[5] = f2bf(b.y); r.s[6] = f2bf(b.z); r.s[7] = f2bf(b.w);
    xb[i] = r.v;
}

// ---------------------------------------------------------------------------
// Kernel 3: C = Xb[8192,4096] @ Wf^T, A staged in LDS (xor-swizzled),
// B loaded flat (fragment-major) global->reg, no LDS for B.
// Grid swizzle: gid&7 selects a 4-tile B column slab (per-XCD L2 ~4.2MB).
// ---------------------------------------------------------------------------
__global__ __launch_bounds__(256) void gemm_flatb_kernel(
        const unsigned short* __restrict__ A,    // Xb row-major
        const unsigned short* __restrict__ Bf,   // W fragment-major
        float* __restrict__ C) {
    __shared__ unsigned short As[128 * 32];      // 8 KiB

    const int t    = threadIdx.x;
    const int lane = t & 63;
    const int wid  = t >> 6;
    const int wm   = wid >> 1;
    const int wn   = wid & 1;

    const int gid   = blockIdx.x;                 // 0..2047
    const int ctile = (gid & 7) * 4 + ((gid >> 3) & 3);   // 0..31
    const int rtile = gid >> 5;                           // 0..63
    const long row0 = (long)rtile * 128;
    const long col0 = (long)ctile * 128;

    // ---- A staging: thread t -> LDS slot (row ar, chunk q), source chunk
    //      q ^ (ar&3) so frag reads are bank-balanced.
    const int ar = t >> 2;                 // local row 0..63 (shot 0)
    const int q  = t & 3;                  // 16B chunk position in row
    const unsigned short* Ag0 = A + (row0 + ar) * H_DIM + ((q ^ (ar & 3)) * 8);
    const unsigned short* Ag1 = Ag0 + 64L * H_DIM;
    unsigned short* Al0 = &As[t * 8];
    unsigned short* Al1 = &As[t * 8 + 2048];

    // ---- B flat pointers: uint4 index = (ct*128 + kc)*64 + lane
    const uint4* Bbase = (const uint4*)Bf +
        ((long)(ctile * 8 + wn * 4) * 128) * 64 + lane;

    f32x4 acc[4][4];
    #pragma unroll
    for (int i = 0; i < 4; ++i)
        #pragma unroll
        for (int j = 0; j < 4; ++j)
            acc[i][j] = (f32x4)0.0f;

    const int fr = lane & 15;
    const int jq = lane >> 4;
    const int achunk = (jq ^ (fr & 3)) * 8;      // xor-unswizzle on read

    for (int kc = 0; kc < H_DIM / 32; ++kc) {
        __syncthreads();                          // prev tile consumed
        gld_lds16(Ag0 + kc * 32, Al0);
        gld_lds16(Ag1 + kc * 32, Al1);

        union { uint4 u; bf16x8 v; } b[4];
        #pragma unroll
        for (int j = 0; j < 4; ++j)
            b[j].u = Bbase[(long)kc * 64 + j * 128 * 64];

        __syncthreads();                          // A staged (drain)

        bf16x8 a[4];
        #pragma unroll
        for (int i = 0; i < 4; ++i) {
            const int r = wm * 64 + i * 16 + fr;
            a[i] = *(const bf16x8*)&As[r * 32 + achunk];
        }

        #pragma unroll
        for (int i = 0; i < 4; ++i)
            #pragma unroll
            for (int j = 0; j < 4; ++j)
                acc[i][j] = __builtin_amdgcn_mfma_f32_16x16x32_bf16(
                                a[i], b[j].v, acc[i][j], 0, 0, 0);
    }

    // epilogue: D col = lane&15, row = (lane>>4)*4 + reg  [m89/m91 verified]
    const int dcol = lane & 15;
    const int drow = (lane >> 4) * 4;
    #pragma unroll
    for (int i = 0; i < 4; ++i) {
        const long r = row0 + wm * 64 + i * 16 + drow;
        #pragma unroll
        for (int j = 0; j < 4; ++j) {
            float* cp = C + r * M_DIM + (col0 + wn * 64 + j * 16 + dcol);
            #pragma unroll
            for (int qq = 0; qq < 4; ++qq)
                cp[qq * (long)M_DIM] = acc[i][j][qq];
        }
    }
}

// ---------------------------------------------------------------------------
// Fallback if ws too small: naive fp32 sparse dot (correct, slow).
// ---------------------------------------------------------------------------
__global__ __launch_bounds__(256) void naive_kernel(
        const float* __restrict__ x, const float* __restrict__ vals,
        const int* __restrict__ cols, float* __restrict__ out) {
    const long idx = blockIdx.x * 256L + threadIdx.x;
    const int  m   = (int)(idx & (M_DIM - 1));
    const long n   = idx >> 12;
    const float* xr = x + n * H_DIM;
    const float* v  = vals + (long)m * NNZ_ROW;
    const int*   c  = cols + (long)m * NNZ_ROW;
    float s = 0.f;
    for (int j = 0; j < NNZ_ROW; ++j) s += v[j] * xr[c[j]];
    out[idx] = s;
}

extern "C" void kernel_launch(void* const* d_in, const int* in_sizes, int n_in,
                              void* d_out, int out_size, void* d_ws, size_t ws_size,
                              hipStream_t stream) {
    const float* x       = (const float*)d_in[0];
    const float* values  = (const float*)d_in[1];
    const int*   col_idx = (const int*)d_in[2];
    float* out = (float*)d_out;

    const size_t wbytes = (size_t)M_DIM * H_DIM * sizeof(unsigned short);   // 33.5 MB
    const size_t xbytes = (size_t)N_ROWS * H_DIM * sizeof(unsigned short);  // 67 MB

    if (ws_size >= wbytes + xbytes) {
        unsigned short* Wf = (unsigned short*)d_ws;
        unsigned short* Xb = (unsigned short*)((char*)d_ws + wbytes);

        decode_w_frag_kernel<<<M_DIM / 4, 256, 0, stream>>>(values, col_idx, Wf);

        const long xvec = (long)N_ROWS * H_DIM / 8;
        convert_x_kernel<<<(int)(xvec / 256), 256, 0, stream>>>(
            (const float4*)x, (uint4*)Xb);

        gemm_flatb_kernel<<<(N_ROWS / 128) * (M_DIM / 128), 256, 0, stream>>>(
            Xb, Wf, out);
    } else {
        naive_kernel<<<(int)((long)N_ROWS * M_DIM / 256), 256, 0, stream>>>(
            x, values, col_idx, out);
    }
}